// Round 2
// baseline (801.093 us; speedup 1.0000x reference)
//
#include <hip/hip_runtime.h>
#include <hip/hip_bf16.h>
#include <stdint.h>

// ---------- problem constants ----------
#define BATCH 32
#define SEQ   1024
#define DIM   1024
#define N3    3072
#define MTOT  (BATCH * SEQ)   // 32768
#define KDIM  1024

// ---------- GEMM tile config (m97 structure) ----------
#define BM 128
#define BN 128
#define BK 32
#define NKT (KDIM / BK)       // 32

typedef __bf16 bf16x8 __attribute__((ext_vector_type(8)));
typedef float  f32x4  __attribute__((ext_vector_type(4)));

__device__ __forceinline__ uint16_t f2b(float f) {
    uint32_t u = __float_as_uint(f);
    u += 0x7fffu + ((u >> 16) & 1u);   // RNE
    return (uint16_t)(u >> 16);
}

__device__ __forceinline__ void async16(void* lds, const void* g) {
    __builtin_amdgcn_global_load_lds((const __attribute__((address_space(1))) void*)g,
                                     (__attribute__((address_space(3))) void*)lds,
                                     16, 0, 0);
}

// ---------------------------------------------------------------------------
// Shared GEMM mainloop: C(128x128) += A[m0..][k] * Bt[n0..][k], lda=ldb=1024.
// A, Bt are bf16 (uint16 storage), row-major with row stride KDIM.
// 256 threads = 4 waves (2x2), each wave 64x64 = 4x4 frags of 16x16.
// Double-buffered LDS, global_load_lds dwordx4 staging, 1 barrier / K-step.
// ---------------------------------------------------------------------------
__device__ __forceinline__ void gemm_core(const uint16_t* __restrict__ A,
                                          const uint16_t* __restrict__ Bt,
                                          int m0, int n0,
                                          f32x4 acc[4][4]) {
    __shared__ uint16_t As[2][BM * BK];   // 8 KB each buf
    __shared__ uint16_t Bs[2][BN * BK];

    const int t    = threadIdx.x;
    const int lane = t & 63;
    const int w    = t >> 6;
    const int wm   = (w >> 1) * 64;
    const int wn   = (w & 1) * 64;
    const int r16  = lane & 15;
    const int g    = lane >> 4;           // 0..3

    // staging: row = t>>2 (and +64), 16B col-seg = t&3
    const int arow = t >> 2;              // 0..63
    const int acs  = t & 3;
    const uint16_t* Ar = A  + (size_t)(m0 + arow) * KDIM + acs * 8;
    const uint16_t* Br = Bt + (size_t)(n0 + arow) * KDIM + acs * 8;

    // prologue: stage tile 0 into buf 0
    {
        async16(&As[0][(size_t)t * 8],        Ar);
        async16(&As[0][(size_t)t * 8 + 2048], Ar + 64 * KDIM);
        async16(&Bs[0][(size_t)t * 8],        Br);
        async16(&Bs[0][(size_t)t * 8 + 2048], Br + 64 * KDIM);
    }
    __syncthreads();   // implicit vmcnt(0)

    int buf = 0;
    for (int kt = 0; kt < NKT; ++kt) {
        if (kt + 1 < NKT) {
            const int ko = (kt + 1) * BK;
            async16(&As[buf ^ 1][(size_t)t * 8],        Ar + ko);
            async16(&As[buf ^ 1][(size_t)t * 8 + 2048], Ar + 64 * KDIM + ko);
            async16(&Bs[buf ^ 1][(size_t)t * 8],        Br + ko);
            async16(&Bs[buf ^ 1][(size_t)t * 8 + 2048], Br + 64 * KDIM + ko);
        }
        const uint16_t* ap = &As[buf][(wm + r16) * BK + g * 8];
        const uint16_t* bp = &Bs[buf][(wn + r16) * BK + g * 8];
        bf16x8 af[4], bfr[4];
#pragma unroll
        for (int i = 0; i < 4; ++i) {
            af[i]  = *(const bf16x8*)(ap + i * 16 * BK);
            bfr[i] = *(const bf16x8*)(bp + i * 16 * BK);
        }
#pragma unroll
        for (int i = 0; i < 4; ++i)
#pragma unroll
            for (int j = 0; j < 4; ++j)
                acc[i][j] = __builtin_amdgcn_mfma_f32_16x16x32_bf16(af[i], bfr[j], acc[i][j], 0, 0, 0);
        __syncthreads();
        buf ^= 1;
    }
}

// ---------------------------------------------------------------------------
// W (f32 [1024][3072]) -> Wt (bf16 [3072][1024])  transpose + convert
// ---------------------------------------------------------------------------
__global__ void k_wt(const float* __restrict__ W, uint16_t* __restrict__ Wt) {
    __shared__ float tile[32][33];
    const int c0 = blockIdx.x * 32;   // N dim (3072)
    const int r0 = blockIdx.y * 32;   // K dim (1024)
    const int tx = threadIdx.x, ty = threadIdx.y;  // 32 x 8
#pragma unroll
    for (int i = 0; i < 32; i += 8)
        tile[ty + i][tx] = W[(size_t)(r0 + ty + i) * N3 + c0 + tx];
    __syncthreads();
#pragma unroll
    for (int i = 0; i < 32; i += 8)
        Wt[(size_t)(c0 + ty + i) * KDIM + r0 + tx] = f2b(tile[tx][ty + i]);
}

// ---------------------------------------------------------------------------
// x (f32) -> bf16, vectorized 8/thread
// ---------------------------------------------------------------------------
__global__ void k_convx(const float* __restrict__ x, uint16_t* __restrict__ xb) {
    const size_t n8 = (size_t)MTOT * KDIM / 8;   // 4,194,304
    size_t i = (size_t)blockIdx.x * blockDim.x + threadIdx.x;
    const size_t stride = (size_t)gridDim.x * blockDim.x;
    for (; i < n8; i += stride) {
        const float4* src = (const float4*)(x + i * 8);
        float4 a = src[0], b = src[1];
        uint32_t p0 = (uint32_t)f2b(a.x) | ((uint32_t)f2b(a.y) << 16);
        uint32_t p1 = (uint32_t)f2b(a.z) | ((uint32_t)f2b(a.w) << 16);
        uint32_t p2 = (uint32_t)f2b(b.x) | ((uint32_t)f2b(b.y) << 16);
        uint32_t p3 = (uint32_t)f2b(b.z) | ((uint32_t)f2b(b.w) << 16);
        uint4 v; v.x = p0; v.y = p1; v.z = p2; v.w = p3;
        ((uint4*)xb)[i] = v;
    }
}

// ---------------------------------------------------------------------------
// QKV GEMM: qkv[m][n] = xb[m][:] . Wt[n][:] + bias[n]
// 1D grid (6144 blocks) with bijective XCD-chunk swizzle (T1):
//   6144 % 8 == 0 -> wgid = (bid%8)*768 + bid/8 is a bijection.
// n in [0,1024) -> Q[b][s][d]; [1024,2048) -> K[b][s][d]; [2048,3072) -> Vt[b][d][s]
// ---------------------------------------------------------------------------
#define QKV_NWG   (MTOT / BM * (N3 / BN))   // 6144
#define QKV_NXT   (N3 / BN)                  // 24 n-tiles
__global__ __launch_bounds__(256, 2)
void k_gemm_qkv(const uint16_t* __restrict__ xb, const uint16_t* __restrict__ Wt,
                const float* __restrict__ bias,
                uint16_t* __restrict__ Qo, uint16_t* __restrict__ Ko,
                uint16_t* __restrict__ Vt) {
    // XCD swizzle: contiguous chunk of 768 tiles per XCD
    const int wgid = (blockIdx.x & 7) * (QKV_NWG / 8) + (blockIdx.x >> 3);
    const int m0 = (wgid / QKV_NXT) * BM;
    const int n0 = (wgid % QKV_NXT) * BN;
    f32x4 acc[4][4] = {};
    gemm_core(xb, Wt, m0, n0, acc);

    const int t = threadIdx.x, lane = t & 63, w = t >> 6;
    const int wm = (w >> 1) * 64, wn = (w & 1) * 64;
    const int r16 = lane & 15, g = lane >> 4;
    const int sec = n0 >> 10;    // tile never straddles a 1024 boundary (128 | 1024)

#pragma unroll
    for (int i = 0; i < 4; ++i) {
#pragma unroll
        for (int j = 0; j < 4; ++j) {
            const int gm = m0 + wm + i * 16 + g * 4;
            const int gn = n0 + wn + j * 16 + r16;
            const float bv = bias[gn];
            const int d = gn & 1023;
#pragma unroll
            for (int r = 0; r < 4; ++r) {
                const uint16_t h = f2b(acc[i][j][r] + bv);
                const int m = gm + r;
                if (sec == 0)      Qo[(size_t)m * 1024 + d] = h;
                else if (sec == 1) Ko[(size_t)m * 1024 + d] = h;
                else {
                    const int b = m >> 10, s = m & 1023;
                    Vt[((size_t)b << 20) + ((size_t)d << 10) + s] = h;
                }
            }
        }
    }
}

// ---------------------------------------------------------------------------
// scores: S[b][q][k] = (Q[b] . K[b]^T) * 1/32   (f32 out)
// ---------------------------------------------------------------------------
__global__ __launch_bounds__(256, 2)
void k_gemm_s(const uint16_t* __restrict__ Q, const uint16_t* __restrict__ Kb,
              float* __restrict__ S) {
    const int b = blockIdx.z;
    const int m0 = blockIdx.y * BM;
    const int n0 = blockIdx.x * BN;
    f32x4 acc[4][4] = {};
    gemm_core(Q + ((size_t)b << 20), Kb + ((size_t)b << 20), m0, n0, acc);

    float* Sb = S + ((size_t)b << 20);
    const int t = threadIdx.x, lane = t & 63, w = t >> 6;
    const int wm = (w >> 1) * 64, wn = (w & 1) * 64;
    const int r16 = lane & 15, g = lane >> 4;
#pragma unroll
    for (int i = 0; i < 4; ++i)
#pragma unroll
        for (int j = 0; j < 4; ++j) {
            const int gm = m0 + wm + i * 16 + g * 4;
            const int gn = n0 + wn + j * 16 + r16;
#pragma unroll
            for (int r = 0; r < 4; ++r)
                Sb[(size_t)(gm + r) * 1024 + gn] = acc[i][j][r] * 0.03125f;
        }
}

// ---------------------------------------------------------------------------
// softmax over rows of S (32768 x 1024), P = softmax(S) as bf16
// ---------------------------------------------------------------------------
__global__ __launch_bounds__(256)
void k_softmax(const float* __restrict__ S, uint16_t* __restrict__ P) {
    const size_t row = blockIdx.x;
    const int t = threadIdx.x, lane = t & 63, w = t >> 6;
    const float4 v = ((const float4*)(S + (row << 10)))[t];

    float m = fmaxf(fmaxf(v.x, v.y), fmaxf(v.z, v.w));
#pragma unroll
    for (int o = 1; o < 64; o <<= 1) m = fmaxf(m, __shfl_xor(m, o));
    __shared__ float redm[4];
    if (lane == 0) redm[w] = m;
    __syncthreads();
    m = fmaxf(fmaxf(redm[0], redm[1]), fmaxf(redm[2], redm[3]));

    const float e0 = __expf(v.x - m), e1 = __expf(v.y - m);
    const float e2 = __expf(v.z - m), e3 = __expf(v.w - m);
    float s = e0 + e1 + e2 + e3;
#pragma unroll
    for (int o = 1; o < 64; o <<= 1) s += __shfl_xor(s, o);
    __shared__ float reds[4];
    if (lane == 0) reds[w] = s;
    __syncthreads();
    s = reds[0] + reds[1] + reds[2] + reds[3];
    const float inv = 1.0f / s;

    const uint64_t pk = (uint64_t)f2b(e0 * inv)
                      | ((uint64_t)f2b(e1 * inv) << 16)
                      | ((uint64_t)f2b(e2 * inv) << 32)
                      | ((uint64_t)f2b(e3 * inv) << 48);
    ((uint64_t*)(P + (row << 10)))[t] = pk;
}

// ---------------------------------------------------------------------------
// out[b][q][d] = P[b] . Vt[b]^T   (f32 out)
// ---------------------------------------------------------------------------
__global__ __launch_bounds__(256, 2)
void k_gemm_pv(const uint16_t* __restrict__ P, const uint16_t* __restrict__ Vt,
               float* __restrict__ out) {
    const int b = blockIdx.z;
    const int m0 = blockIdx.y * BM;
    const int n0 = blockIdx.x * BN;
    f32x4 acc[4][4] = {};
    gemm_core(P + ((size_t)b << 20), Vt + ((size_t)b << 20), m0, n0, acc);

    float* Ob = out + ((size_t)b << 20);
    const int t = threadIdx.x, lane = t & 63, w = t >> 6;
    const int wm = (w >> 1) * 64, wn = (w & 1) * 64;
    const int r16 = lane & 15, g = lane >> 4;
#pragma unroll
    for (int i = 0; i < 4; ++i)
#pragma unroll
        for (int j = 0; j < 4; ++j) {
            const int gm = m0 + wm + i * 16 + g * 4;
            const int gn = n0 + wn + j * 16 + r16;
#pragma unroll
            for (int r = 0; r < 4; ++r)
                Ob[(size_t)(gm + r) * 1024 + gn] = acc[i][j][r];
        }
}

// ---------------------------------------------------------------------------
extern "C" void kernel_launch(void* const* d_in, const int* in_sizes, int n_in,
                              void* d_out, int out_size, void* d_ws, size_t ws_size,
                              hipStream_t stream) {
    const float* x    = (const float*)d_in[0];   // [32][1024][1024]
    const float* W    = (const float*)d_in[1];   // [1024][3072]
    const float* bias = (const float*)d_in[2];   // [3072]
    float* out = (float*)d_out;

    char* ws = (char*)d_ws;
    const size_t MB = 1ull << 20;
    uint16_t* Wt = (uint16_t*)(ws);               //   6 MB: [3072][1024] bf16
    uint16_t* xb = (uint16_t*)(ws + 6   * MB);    //  64 MB: [32768][1024] bf16
    uint16_t* Qo = (uint16_t*)(ws + 70  * MB);    //  64 MB
    uint16_t* Ko = (uint16_t*)(ws + 134 * MB);    //  64 MB
    uint16_t* Vt = (uint16_t*)(ws + 198 * MB);    //  64 MB: [b][d][s]
    float*    S  = (float*)   (ws + 262 * MB);    // 128 MB: [b][q][k] f32
    uint16_t* P  = (uint16_t*)(ws + 390 * MB);    //  64 MB
    // total 454 MB of ws

    k_wt    <<<dim3(N3 / 32, KDIM / 32), dim3(32, 8), 0, stream>>>(W, Wt);
    k_convx <<<8192, 256, 0, stream>>>(x, xb);
    k_gemm_qkv<<<QKV_NWG, 256, 0, stream>>>(xb, Wt, bias, Qo, Ko, Vt);
    k_gemm_s  <<<dim3(SEQ / BN, SEQ / BM, BATCH), 256, 0, stream>>>(Qo, Ko, S);
    k_softmax <<<MTOT, 256, 0, stream>>>(S, P);
    k_gemm_pv <<<dim3(DIM / BN, SEQ / BM, BATCH), 256, 0, stream>>>(P, Vt, out);
}

// Round 3
// 730.690 us; speedup vs baseline: 1.0964x; 1.0964x over previous
//
#include <hip/hip_runtime.h>
#include <hip/hip_bf16.h>
#include <stdint.h>

// ---------- problem constants ----------
#define BATCH 32
#define SEQ   1024
#define DIM   1024
#define N3    3072
#define MTOT  (BATCH * SEQ)   // 32768
#define KDIM  1024
#define NT    16              // K-tiles of 64 (K=1024)

typedef __bf16 bf16x8 __attribute__((ext_vector_type(8)));
typedef float  f32x4  __attribute__((ext_vector_type(4)));

__device__ __forceinline__ uint16_t f2b(float f) {
    uint32_t u = __float_as_uint(f);
    u += 0x7fffu + ((u >> 16) & 1u);   // RNE
    return (uint16_t)(u >> 16);
}

__device__ __forceinline__ void async16(void* lds, const void* g) {
    __builtin_amdgcn_global_load_lds((const __attribute__((address_space(1))) void*)g,
                                     (__attribute__((address_space(3))) void*)lds,
                                     16, 0, 0);
}

// ---------------------------------------------------------------------------
// 256x256 8-phase GEMM core (T2 swizzle + T3/T4 counted vmcnt + T5 setprio).
// C(256x256) += A[m0..][k] * Bt[n0..][k], row stride KDIM, bf16 in, f32 acc.
// 512 threads = 8 waves (2m x 4n). Per K-tile (BK=64): 4 phases, phase q
// computes C-quadrant (A-half AH[q], B-half BH[q]) = 16 MFMA/wave, reads
// 12 ds_read_b128, stages 1 half-tile of K-tile t+1 (2 global_load_lds).
// LDS 128 KiB: 2 bufs x (A 32KB + B 32KB). Row = 128B, phys 16B-slot =
// kseg ^ (row&7); global source pre-swizzled, gload_lds dest linear.
// vmcnt(4) per phase steady state; last iter drains 4/2/0/0.
// Safety: stage into buf b only after all reads of b completed (>=1 barrier
// between last read and stage issue); wave skew bounded <1 phase by barrier.
// ---------------------------------------------------------------------------
#define GPHASE(q, AH, BH)                                                          \
  {                                                                                \
    if (st) { asm volatile("s_waitcnt vmcnt(4)" ::: "memory"); }                   \
    else if (q == 0) { asm volatile("s_waitcnt vmcnt(4)" ::: "memory"); }          \
    else if (q == 1) { asm volatile("s_waitcnt vmcnt(2)" ::: "memory"); }          \
    else             { asm volatile("s_waitcnt vmcnt(0)" ::: "memory"); }          \
    __builtin_amdgcn_s_barrier();                                                  \
    asm volatile("" ::: "memory");                                                 \
    if (st) {                                                                      \
      if      (q == 0) stage(A,  m0,       kn, nbuf);                              \
      else if (q == 1) stage(Bt, n0,       kn, nbuf + 16384);                      \
      else if (q == 2) stage(Bt, n0 + 128, kn, nbuf + 16384 + 8192);               \
      else             stage(A,  m0 + 128, kn, nbuf + 8192);                       \
    }                                                                              \
    const uint16_t* Abase = bufA + (AH) * 8192 + wm * 64 * 64;                     \
    const uint16_t* Bbase = bufB + (BH) * 8192 + wn * 32 * 64;                     \
    bf16x8 af0[2], af1[2], af2[2], af3[2], bg0[2], bg1[2];                         \
    _Pragma("unroll")                                                              \
    for (int ks = 0; ks < 2; ++ks) {                                               \
      const int sw = (((ks * 4 + g) ^ (r16 & 7)) * 8);                             \
      af0[ks] = *(const bf16x8*)(Abase + (r16      ) * 64 + sw);                   \
      af1[ks] = *(const bf16x8*)(Abase + (r16 +  16) * 64 + sw);                   \
      af2[ks] = *(const bf16x8*)(Abase + (r16 +  32) * 64 + sw);                   \
      af3[ks] = *(const bf16x8*)(Abase + (r16 +  48) * 64 + sw);                   \
      bg0[ks] = *(const bf16x8*)(Bbase + (r16      ) * 64 + sw);                   \
      bg1[ks] = *(const bf16x8*)(Bbase + (r16 +  16) * 64 + sw);                   \
    }                                                                              \
    __builtin_amdgcn_s_setprio(1);                                                 \
    _Pragma("unroll")                                                              \
    for (int ks = 0; ks < 2; ++ks) {                                               \
      acc[q][0][0] = __builtin_amdgcn_mfma_f32_16x16x32_bf16(af0[ks], bg0[ks], acc[q][0][0], 0,0,0); \
      acc[q][0][1] = __builtin_amdgcn_mfma_f32_16x16x32_bf16(af0[ks], bg1[ks], acc[q][0][1], 0,0,0); \
      acc[q][1][0] = __builtin_amdgcn_mfma_f32_16x16x32_bf16(af1[ks], bg0[ks], acc[q][1][0], 0,0,0); \
      acc[q][1][1] = __builtin_amdgcn_mfma_f32_16x16x32_bf16(af1[ks], bg1[ks], acc[q][1][1], 0,0,0); \
      acc[q][2][0] = __builtin_amdgcn_mfma_f32_16x16x32_bf16(af2[ks], bg0[ks], acc[q][2][0], 0,0,0); \
      acc[q][2][1] = __builtin_amdgcn_mfma_f32_16x16x32_bf16(af2[ks], bg1[ks], acc[q][2][1], 0,0,0); \
      acc[q][3][0] = __builtin_amdgcn_mfma_f32_16x16x32_bf16(af3[ks], bg0[ks], acc[q][3][0], 0,0,0); \
      acc[q][3][1] = __builtin_amdgcn_mfma_f32_16x16x32_bf16(af3[ks], bg1[ks], acc[q][3][1], 0,0,0); \
    }                                                                              \
    __builtin_amdgcn_s_setprio(0);                                                 \
  }

__device__ __forceinline__ void gemm256_core(const uint16_t* __restrict__ A,
                                             const uint16_t* __restrict__ Bt,
                                             const int m0, const int n0,
                                             f32x4 (&acc)[4][4][2]) {
    __shared__ __align__(16) uint16_t sm[65536];   // 128 KiB
    const int tid  = threadIdx.x;
    const int lane = tid & 63;
    const int w    = tid >> 6;
    const int wm   = w >> 2;          // 0..1
    const int wn   = w & 3;           // 0..3
    const int r16  = lane & 15;
    const int g    = lane >> 4;       // 0..3

    // stage one half-tile (128 rows x 64 k) -> linear LDS dest,
    // pre-swizzled global source (phys slot = kseg ^ (row&7))
    auto stage = [&](const uint16_t* mat, int row0, int k0, uint16_t* ldsHalf) {
#pragma unroll
        for (int l = 0; l < 2; ++l) {
            const int idx  = l * 512 + tid;         // 0..1023
            const int r    = idx >> 3;              // 0..127
            const int kseg = (idx & 7) ^ (r & 7);
            async16(ldsHalf + idx * 8,
                    mat + (size_t)(row0 + r) * KDIM + k0 + kseg * 8);
        }
    };

    // prologue: K-tile 0 into buf0, order A0,B0,B1,A1
    stage(A,  m0,       0, sm);
    stage(Bt, n0,       0, sm + 16384);
    stage(Bt, n0 + 128, 0, sm + 16384 + 8192);
    stage(A,  m0 + 128, 0, sm + 8192);

    for (int t = 0; t < NT; ++t) {
        const uint16_t* bufA = sm + (t & 1) * 32768;
        const uint16_t* bufB = bufA + 16384;
        uint16_t* nbuf = sm + ((t + 1) & 1) * 32768;
        const bool st = (t + 1 < NT);
        const int kn = ((t + 1) & (NT - 1)) * 64;
        GPHASE(0, 0, 0)
        GPHASE(1, 0, 1)
        GPHASE(2, 1, 1)
        GPHASE(3, 1, 0)
    }
}

// epilogue index helpers: quadrant q covers rows AH[q]*128+wm*64, cols BH[q]*128+wn*32
__device__ __forceinline__ int ep_row(int q, int wm, int g, int fi, int r) {
    const int AH[4] = {0, 0, 1, 1};
    return AH[q] * 128 + wm * 64 + fi * 16 + g * 4 + r;
}
__device__ __forceinline__ int ep_col(int q, int wn, int r16, int fj) {
    const int BH[4] = {0, 1, 1, 0};
    return BH[q] * 128 + wn * 32 + fj * 16 + r16;
}

// ---------------------------------------------------------------------------
// W (f32 [1024][3072]) -> Wt (bf16 [3072][1024])  transpose + convert
// ---------------------------------------------------------------------------
__global__ void k_wt(const float* __restrict__ W, uint16_t* __restrict__ Wt) {
    __shared__ float tile[32][33];
    const int c0 = blockIdx.x * 32;
    const int r0 = blockIdx.y * 32;
    const int tx = threadIdx.x, ty = threadIdx.y;  // 32 x 8
#pragma unroll
    for (int i = 0; i < 32; i += 8)
        tile[ty + i][tx] = W[(size_t)(r0 + ty + i) * N3 + c0 + tx];
    __syncthreads();
#pragma unroll
    for (int i = 0; i < 32; i += 8)
        Wt[(size_t)(c0 + ty + i) * KDIM + r0 + tx] = f2b(tile[tx][ty + i]);
}

// ---------------------------------------------------------------------------
// x (f32) -> bf16, vectorized 8/thread
// ---------------------------------------------------------------------------
__global__ void k_convx(const float* __restrict__ x, uint16_t* __restrict__ xb) {
    const size_t n8 = (size_t)MTOT * KDIM / 8;
    size_t i = (size_t)blockIdx.x * blockDim.x + threadIdx.x;
    const size_t stride = (size_t)gridDim.x * blockDim.x;
    for (; i < n8; i += stride) {
        const float4* src = (const float4*)(x + i * 8);
        float4 a = src[0], b = src[1];
        uint32_t p0 = (uint32_t)f2b(a.x) | ((uint32_t)f2b(a.y) << 16);
        uint32_t p1 = (uint32_t)f2b(a.z) | ((uint32_t)f2b(a.w) << 16);
        uint32_t p2 = (uint32_t)f2b(b.x) | ((uint32_t)f2b(b.y) << 16);
        uint32_t p3 = (uint32_t)f2b(b.z) | ((uint32_t)f2b(b.w) << 16);
        uint4 v; v.x = p0; v.y = p1; v.z = p2; v.w = p3;
        ((uint4*)xb)[i] = v;
    }
}

// ---------------------------------------------------------------------------
// QKV GEMM (256x256 tiles): grid 1536 = 128 m x 12 n, XCD-chunk swizzle.
// ---------------------------------------------------------------------------
#define QKV_NWG  ((MTOT / 256) * (N3 / 256))   // 1536
#define QKV_NXT  (N3 / 256)                    // 12
__global__ __launch_bounds__(512, 2)
void k_gemm_qkv(const uint16_t* __restrict__ xb, const uint16_t* __restrict__ Wt,
                const float* __restrict__ bias,
                uint16_t* __restrict__ Qo, uint16_t* __restrict__ Ko,
                uint16_t* __restrict__ Vt) {
    const int wgid = (blockIdx.x & 7) * (QKV_NWG / 8) + (blockIdx.x >> 3);
    const int m0 = (wgid / QKV_NXT) * 256;
    const int n0 = (wgid % QKV_NXT) * 256;
    f32x4 acc[4][4][2] = {};
    gemm256_core(xb, Wt, m0, n0, acc);

    const int tid = threadIdx.x, lane = tid & 63, w = tid >> 6;
    const int wm = w >> 2, wn = w & 3, r16 = lane & 15, g = lane >> 4;
    const int sec = n0 >> 10;   // 256-tile never straddles a 1024 boundary

#pragma unroll
    for (int q = 0; q < 4; ++q)
#pragma unroll
        for (int fi = 0; fi < 4; ++fi)
#pragma unroll
            for (int fj = 0; fj < 2; ++fj) {
                const int col = n0 + ep_col(q, wn, r16, fj);
                const float bv = bias[col];
                const int d = col & 1023;
#pragma unroll
                for (int r = 0; r < 4; ++r) {
                    const int m = m0 + ep_row(q, wm, g, fi, r);
                    const uint16_t h = f2b(acc[q][fi][fj][r] + bv);
                    if (sec == 0)      Qo[(size_t)m * 1024 + d] = h;
                    else if (sec == 1) Ko[(size_t)m * 1024 + d] = h;
                    else {
                        const int b = m >> 10, s = m & 1023;
                        Vt[((size_t)b << 20) + ((size_t)d << 10) + s] = h;
                    }
                }
            }
}

// ---------------------------------------------------------------------------
// scores: S[b][q][k] = (Q[b] . K[b]^T) * 1/32   (f32 out)
// ---------------------------------------------------------------------------
__global__ __launch_bounds__(512, 2)
void k_gemm_s(const uint16_t* __restrict__ Q, const uint16_t* __restrict__ Kb,
              float* __restrict__ S) {
    const int b = blockIdx.z;
    const int m0 = blockIdx.y * 256;
    const int n0 = blockIdx.x * 256;
    f32x4 acc[4][4][2] = {};
    gemm256_core(Q + ((size_t)b << 20), Kb + ((size_t)b << 20), m0, n0, acc);

    float* Sb = S + ((size_t)b << 20);
    const int tid = threadIdx.x, lane = tid & 63, w = tid >> 6;
    const int wm = w >> 2, wn = w & 3, r16 = lane & 15, g = lane >> 4;
#pragma unroll
    for (int q = 0; q < 4; ++q)
#pragma unroll
        for (int fi = 0; fi < 4; ++fi)
#pragma unroll
            for (int fj = 0; fj < 2; ++fj) {
                const int col = n0 + ep_col(q, wn, r16, fj);
#pragma unroll
                for (int r = 0; r < 4; ++r) {
                    const int row = m0 + ep_row(q, wm, g, fi, r);
                    Sb[(size_t)row * 1024 + col] = acc[q][fi][fj][r] * 0.03125f;
                }
            }
}

// ---------------------------------------------------------------------------
// softmax over rows of S (32768 x 1024), P = softmax(S) as bf16
// ---------------------------------------------------------------------------
__global__ __launch_bounds__(256)
void k_softmax(const float* __restrict__ S, uint16_t* __restrict__ P) {
    const size_t row = blockIdx.x;
    const int t = threadIdx.x, lane = t & 63, w = t >> 6;
    const float4 v = ((const float4*)(S + (row << 10)))[t];

    float m = fmaxf(fmaxf(v.x, v.y), fmaxf(v.z, v.w));
#pragma unroll
    for (int o = 1; o < 64; o <<= 1) m = fmaxf(m, __shfl_xor(m, o));
    __shared__ float redm[4];
    if (lane == 0) redm[w] = m;
    __syncthreads();
    m = fmaxf(fmaxf(redm[0], redm[1]), fmaxf(redm[2], redm[3]));

    const float e0 = __expf(v.x - m), e1 = __expf(v.y - m);
    const float e2 = __expf(v.z - m), e3 = __expf(v.w - m);
    float s = e0 + e1 + e2 + e3;
#pragma unroll
    for (int o = 1; o < 64; o <<= 1) s += __shfl_xor(s, o);
    __shared__ float reds[4];
    if (lane == 0) reds[w] = s;
    __syncthreads();
    s = reds[0] + reds[1] + reds[2] + reds[3];
    const float inv = 1.0f / s;

    const uint64_t pk = (uint64_t)f2b(e0 * inv)
                      | ((uint64_t)f2b(e1 * inv) << 16)
                      | ((uint64_t)f2b(e2 * inv) << 32)
                      | ((uint64_t)f2b(e3 * inv) << 48);
    ((uint64_t*)(P + (row << 10)))[t] = pk;
}

// ---------------------------------------------------------------------------
// out[b][q][d] = P[b] . Vt[b]^T   (f32 out)
// ---------------------------------------------------------------------------
__global__ __launch_bounds__(512, 2)
void k_gemm_pv(const uint16_t* __restrict__ P, const uint16_t* __restrict__ Vt,
               float* __restrict__ out) {
    const int b = blockIdx.z;
    const int m0 = blockIdx.y * 256;
    const int n0 = blockIdx.x * 256;
    f32x4 acc[4][4][2] = {};
    gemm256_core(P + ((size_t)b << 20), Vt + ((size_t)b << 20), m0, n0, acc);

    float* Ob = out + ((size_t)b << 20);
    const int tid = threadIdx.x, lane = tid & 63, w = tid >> 6;
    const int wm = w >> 2, wn = w & 3, r16 = lane & 15, g = lane >> 4;
#pragma unroll
    for (int q = 0; q < 4; ++q)
#pragma unroll
        for (int fi = 0; fi < 4; ++fi)
#pragma unroll
            for (int fj = 0; fj < 2; ++fj) {
                const int col = n0 + ep_col(q, wn, r16, fj);
#pragma unroll
                for (int r = 0; r < 4; ++r) {
                    const int row = m0 + ep_row(q, wm, g, fi, r);
                    Ob[(size_t)row * 1024 + col] = acc[q][fi][fj][r];
                }
            }
}

// ---------------------------------------------------------------------------
extern "C" void kernel_launch(void* const* d_in, const int* in_sizes, int n_in,
                              void* d_out, int out_size, void* d_ws, size_t ws_size,
                              hipStream_t stream) {
    const float* x    = (const float*)d_in[0];   // [32][1024][1024]
    const float* W    = (const float*)d_in[1];   // [1024][3072]
    const float* bias = (const float*)d_in[2];   // [3072]
    float* out = (float*)d_out;

    char* ws = (char*)d_ws;
    const size_t MB = 1ull << 20;
    uint16_t* Wt = (uint16_t*)(ws);               //   6 MB: [3072][1024] bf16
    uint16_t* xb = (uint16_t*)(ws + 6   * MB);    //  64 MB: [32768][1024] bf16
    uint16_t* Qo = (uint16_t*)(ws + 70  * MB);    //  64 MB
    uint16_t* Ko = (uint16_t*)(ws + 134 * MB);    //  64 MB
    uint16_t* Vt = (uint16_t*)(ws + 198 * MB);    //  64 MB: [b][d][s]
    float*    S  = (float*)   (ws + 262 * MB);    // 128 MB: [b][q][k] f32
    uint16_t* P  = (uint16_t*)(ws + 390 * MB);    //  64 MB
    // total 454 MB of ws

    k_wt    <<<dim3(N3 / 32, KDIM / 32), dim3(32, 8), 0, stream>>>(W, Wt);
    k_convx <<<8192, 256, 0, stream>>>(x, xb);
    k_gemm_qkv<<<QKV_NWG, 512, 0, stream>>>(xb, Wt, bias, Qo, Ko, Vt);
    k_gemm_s  <<<dim3(SEQ / 256, SEQ / 256, BATCH), 512, 0, stream>>>(Qo, Ko, S);
    k_softmax <<<MTOT, 256, 0, stream>>>(S, P);
    k_gemm_pv <<<dim3(DIM / 256, SEQ / 256, BATCH), 512, 0, stream>>>(P, Vt, out);
}

// Round 6
// 703.110 us; speedup vs baseline: 1.1394x; 1.0392x over previous
//
#include <hip/hip_runtime.h>
#include <hip/hip_bf16.h>
#include <stdint.h>

// ---------- problem constants ----------
#define BATCH 32
#define SEQ   1024
#define DIM   1024
#define N3    3072
#define MTOT  (BATCH * SEQ)   // 32768
#define KDIM  1024
#define NT    16              // K-tiles of 64 (K=1024)

typedef __bf16 bf16x8 __attribute__((ext_vector_type(8)));
typedef float  f32x4  __attribute__((ext_vector_type(4)));

__device__ __forceinline__ uint16_t f2b(float f) {
    uint32_t u = __float_as_uint(f);
    u += 0x7fffu + ((u >> 16) & 1u);   // RNE
    return (uint16_t)(u >> 16);
}

__device__ __forceinline__ void async16(void* lds, const void* g) {
    __builtin_amdgcn_global_load_lds((const __attribute__((address_space(1))) void*)g,
                                     (__attribute__((address_space(3))) void*)lds,
                                     16, 0, 0);
}

// ---------------------------------------------------------------------------
// 256x256 8-wave GEMM core, register-resident fragments (fix for LDS-BW bound):
// per K-tile (BK=64) 4 phases, LDS reads 12/4/8/0 = 24 ds_read_b128/wave/K-tile
// (minimal; was 48). A-half lives in aF across 2 phases; both B-halves live in
// bF0/bF1. Quadrant q -> acc[q]: (AH,BH) = (0,0),(0,1),(1,1),(1,0).
// Sync: vmcnt(N) + s_barrier BEFORE any phase that ds_reads staged data
// (barrier needed for cross-wave staging visibility; vmcnt is per-wave).
// Phase 3 is register-only: no wait, no barrier. 3 barriers/K-tile.
// Staging: 1 half-tile (2 global_load_lds dwordx4/thread) per phase into the
// other buffer; steady-state depth 8 loads -> uniform vmcnt(4); drain 4/2/0.
// T2 XOR swizzle: phys 16B-slot = kseg ^ (row&7), pre-swizzled global source,
// linear gload_lds dest (rule 21). T5 setprio around each 16-MFMA cluster.
// ---------------------------------------------------------------------------
__device__ __forceinline__ void gemm256_core(const uint16_t* __restrict__ A,
                                             const uint16_t* __restrict__ Bt,
                                             const int m0, const int n0,
                                             f32x4 (&acc)[4][4][2]) {
    __shared__ __align__(16) uint16_t sm[65536];   // 128 KiB
    const int tid  = threadIdx.x;
    const int lane = tid & 63;
    const int w    = tid >> 6;
    const int wm   = w >> 2;          // 0..1
    const int wn   = w & 3;           // 0..3
    const int r16  = lane & 15;
    const int g    = lane >> 4;       // 0..3

    auto stage = [&](const uint16_t* mat, int row0, int k0, uint16_t* ldsHalf) {
#pragma unroll
        for (int l = 0; l < 2; ++l) {
            const int idx  = l * 512 + tid;         // 0..1023
            const int r    = idx >> 3;              // 0..127
            const int kseg = (idx & 7) ^ (r & 7);
            async16(ldsHalf + idx * 8,
                    mat + (size_t)(row0 + r) * KDIM + k0 + kseg * 8);
        }
    };

    // prologue: K-tile 0 into buf0, order A0,B0,B1,A1
    stage(A,  m0,       0, sm);
    stage(Bt, n0,       0, sm + 16384);
    stage(Bt, n0 + 128, 0, sm + 16384 + 8192);
    stage(A,  m0 + 128, 0, sm + 8192);

    bf16x8 aF[2][4];            // current A-half fragments [ks][row-group]
    bf16x8 bF0[2][2], bF1[2][2];// B-half fragments [ks][col-group], both live

#define LOAD_A(half)                                                      \
    {   const uint16_t* Ab = bufA + (half) * 8192 + wm * 64 * 64;         \
        _Pragma("unroll")                                                 \
        for (int ks = 0; ks < 2; ++ks) {                                  \
            const int sw = (((ks * 4 + g) ^ (r16 & 7)) * 8);              \
            aF[ks][0] = *(const bf16x8*)(Ab + (r16      ) * 64 + sw);     \
            aF[ks][1] = *(const bf16x8*)(Ab + (r16 + 16) * 64 + sw);      \
            aF[ks][2] = *(const bf16x8*)(Ab + (r16 + 32) * 64 + sw);      \
            aF[ks][3] = *(const bf16x8*)(Ab + (r16 + 48) * 64 + sw);      \
        } }
#define LOAD_B(dst, half)                                                 \
    {   const uint16_t* Bb = bufB + (half) * 8192 + wn * 32 * 64;         \
        _Pragma("unroll")                                                 \
        for (int ks = 0; ks < 2; ++ks) {                                  \
            const int sw = (((ks * 4 + g) ^ (r16 & 7)) * 8);              \
            dst[ks][0] = *(const bf16x8*)(Bb + (r16      ) * 64 + sw);    \
            dst[ks][1] = *(const bf16x8*)(Bb + (r16 + 16) * 64 + sw);     \
        } }
#define MFMA16(q, B)                                                      \
    __builtin_amdgcn_s_setprio(1);                                        \
    _Pragma("unroll")                                                     \
    for (int ks = 0; ks < 2; ++ks) {                                      \
        _Pragma("unroll")                                                 \
        for (int fi = 0; fi < 4; ++fi) {                                  \
            acc[q][fi][0] = __builtin_amdgcn_mfma_f32_16x16x32_bf16(aF[ks][fi], B[ks][0], acc[q][fi][0], 0,0,0); \
            acc[q][fi][1] = __builtin_amdgcn_mfma_f32_16x16x32_bf16(aF[ks][fi], B[ks][1], acc[q][fi][1], 0,0,0); \
        } }                                                               \
    __builtin_amdgcn_s_setprio(0);

    for (int t = 0; t < NT; ++t) {
        const uint16_t* bufA = sm + (t & 1) * 32768;
        const uint16_t* bufB = bufA + 16384;
        uint16_t* nbuf = sm + ((t + 1) & 1) * 32768;
        const bool st = (t + 1 < NT);
        const int kn = ((t + 1) & (NT - 1)) * 64;

        // ---- phase 0: quad (A0,B0); loads 8+4
        asm volatile("s_waitcnt vmcnt(4)" ::: "memory");
        __builtin_amdgcn_s_barrier();
        if (st) stage(A, m0, kn, nbuf);
        LOAD_A(0)
        LOAD_B(bF0, 0)
        MFMA16(0, bF0)

        // ---- phase 1: quad (A0,B1); loads 4 (aF reused)
        if (st) { asm volatile("s_waitcnt vmcnt(4)" ::: "memory"); }
        else    { asm volatile("s_waitcnt vmcnt(2)" ::: "memory"); }
        __builtin_amdgcn_s_barrier();
        if (st) stage(Bt, n0, kn, nbuf + 16384);
        LOAD_B(bF1, 1)
        MFMA16(1, bF1)

        // ---- phase 2: quad (A1,B1); loads 8 (bF1 reused)
        if (st) { asm volatile("s_waitcnt vmcnt(4)" ::: "memory"); }
        else    { asm volatile("s_waitcnt vmcnt(0)" ::: "memory"); }
        __builtin_amdgcn_s_barrier();
        if (st) stage(Bt, n0 + 128, kn, nbuf + 16384 + 8192);
        LOAD_A(1)
        MFMA16(2, bF1)

        // ---- phase 3: quad (A1,B0); register-only -> no wait/barrier
        if (st) stage(A, m0 + 128, kn, nbuf + 8192);
        MFMA16(3, bF0)
    }
#undef LOAD_A
#undef LOAD_B
#undef MFMA16
}

// epilogue index helpers: quadrant q covers rows AH[q]*128+wm*64, cols BH[q]*128+wn*32
__device__ __forceinline__ int ep_row(int q, int wm, int g, int fi, int r) {
    const int AH[4] = {0, 0, 1, 1};
    return AH[q] * 128 + wm * 64 + fi * 16 + g * 4 + r;
}
__device__ __forceinline__ int ep_col(int q, int wn, int r16, int fj) {
    const int BH[4] = {0, 1, 1, 0};
    return BH[q] * 128 + wn * 32 + fj * 16 + r16;
}

// ---------------------------------------------------------------------------
// W (f32 [1024][3072]) -> Wt (bf16 [3072][1024])  transpose + convert
// ---------------------------------------------------------------------------
__global__ void k_wt(const float* __restrict__ W, uint16_t* __restrict__ Wt) {
    __shared__ float tile[32][33];
    const int c0 = blockIdx.x * 32;
    const int r0 = blockIdx.y * 32;
    const int tx = threadIdx.x, ty = threadIdx.y;  // 32 x 8
#pragma unroll
    for (int i = 0; i < 32; i += 8)
        tile[ty + i][tx] = W[(size_t)(r0 + ty + i) * N3 + c0 + tx];
    __syncthreads();
#pragma unroll
    for (int i = 0; i < 32; i += 8)
        Wt[(size_t)(c0 + ty + i) * KDIM + r0 + tx] = f2b(tile[tx][ty + i]);
}

// ---------------------------------------------------------------------------
// x (f32) -> bf16, vectorized 8/thread
// ---------------------------------------------------------------------------
__global__ void k_convx(const float* __restrict__ x, uint16_t* __restrict__ xb) {
    const size_t n8 = (size_t)MTOT * KDIM / 8;
    size_t i = (size_t)blockIdx.x * blockDim.x + threadIdx.x;
    const size_t stride = (size_t)gridDim.x * blockDim.x;
    for (; i < n8; i += stride) {
        const float4* src = (const float4*)(x + i * 8);
        float4 a = src[0], b = src[1];
        uint32_t p0 = (uint32_t)f2b(a.x) | ((uint32_t)f2b(a.y) << 16);
        uint32_t p1 = (uint32_t)f2b(a.z) | ((uint32_t)f2b(a.w) << 16);
        uint32_t p2 = (uint32_t)f2b(b.x) | ((uint32_t)f2b(b.y) << 16);
        uint32_t p3 = (uint32_t)f2b(b.z) | ((uint32_t)f2b(b.w) << 16);
        uint4 v; v.x = p0; v.y = p1; v.z = p2; v.w = p3;
        ((uint4*)xb)[i] = v;
    }
}

// ---------------------------------------------------------------------------
// QKV GEMM (256x256 tiles): grid 1536 = 128 m x 12 n, XCD-chunk swizzle.
// ---------------------------------------------------------------------------
#define QKV_NWG  ((MTOT / 256) * (N3 / 256))   // 1536
#define QKV_NXT  (N3 / 256)                    // 12
__global__ __launch_bounds__(512, 2)
void k_gemm_qkv(const uint16_t* __restrict__ xb, const uint16_t* __restrict__ Wt,
                const float* __restrict__ bias,
                uint16_t* __restrict__ Qo, uint16_t* __restrict__ Ko,
                uint16_t* __restrict__ Vt) {
    const int wgid = (blockIdx.x & 7) * (QKV_NWG / 8) + (blockIdx.x >> 3);
    const int m0 = (wgid / QKV_NXT) * 256;
    const int n0 = (wgid % QKV_NXT) * 256;
    f32x4 acc[4][4][2] = {};
    gemm256_core(xb, Wt, m0, n0, acc);

    const int tid = threadIdx.x, lane = tid & 63, w = tid >> 6;
    const int wm = w >> 2, wn = w & 3, r16 = lane & 15, g = lane >> 4;
    const int sec = n0 >> 10;   // 256-tile never straddles a 1024 boundary

#pragma unroll
    for (int q = 0; q < 4; ++q)
#pragma unroll
        for (int fi = 0; fi < 4; ++fi)
#pragma unroll
            for (int fj = 0; fj < 2; ++fj) {
                const int col = n0 + ep_col(q, wn, r16, fj);
                const float bv = bias[col];
                const int d = col & 1023;
#pragma unroll
                for (int r = 0; r < 4; ++r) {
                    const int m = m0 + ep_row(q, wm, g, fi, r);
                    const uint16_t h = f2b(acc[q][fi][fj][r] + bv);
                    if (sec == 0)      Qo[(size_t)m * 1024 + d] = h;
                    else if (sec == 1) Ko[(size_t)m * 1024 + d] = h;
                    else {
                        const int b = m >> 10, s = m & 1023;
                        Vt[((size_t)b << 20) + ((size_t)d << 10) + s] = h;
                    }
                }
            }
}

// ---------------------------------------------------------------------------
// scores: S[b][q][k] = (Q[b] . K[b]^T) * 1/32   (f32 out)
// ---------------------------------------------------------------------------
__global__ __launch_bounds__(512, 2)
void k_gemm_s(const uint16_t* __restrict__ Q, const uint16_t* __restrict__ Kb,
              float* __restrict__ S) {
    const int b = blockIdx.z;
    const int m0 = blockIdx.y * 256;
    const int n0 = blockIdx.x * 256;
    f32x4 acc[4][4][2] = {};
    gemm256_core(Q + ((size_t)b << 20), Kb + ((size_t)b << 20), m0, n0, acc);

    float* Sb = S + ((size_t)b << 20);
    const int tid = threadIdx.x, lane = tid & 63, w = tid >> 6;
    const int wm = w >> 2, wn = w & 3, r16 = lane & 15, g = lane >> 4;
#pragma unroll
    for (int q = 0; q < 4; ++q)
#pragma unroll
        for (int fi = 0; fi < 4; ++fi)
#pragma unroll
            for (int fj = 0; fj < 2; ++fj) {
                const int col = n0 + ep_col(q, wn, r16, fj);
#pragma unroll
                for (int r = 0; r < 4; ++r) {
                    const int row = m0 + ep_row(q, wm, g, fi, r);
                    Sb[(size_t)row * 1024 + col] = acc[q][fi][fj][r] * 0.03125f;
                }
            }
}

// ---------------------------------------------------------------------------
// softmax over rows of S (32768 x 1024), P = softmax(S) as bf16
// ---------------------------------------------------------------------------
__global__ __launch_bounds__(256)
void k_softmax(const float* __restrict__ S, uint16_t* __restrict__ P) {
    const size_t row = blockIdx.x;
    const int t = threadIdx.x, lane = t & 63, w = t >> 6;
    const float4 v = ((const float4*)(S + (row << 10)))[t];

    float m = fmaxf(fmaxf(v.x, v.y), fmaxf(v.z, v.w));
#pragma unroll
    for (int o = 1; o < 64; o <<= 1) m = fmaxf(m, __shfl_xor(m, o));
    __shared__ float redm[4];
    if (lane == 0) redm[w] = m;
    __syncthreads();
    m = fmaxf(fmaxf(redm[0], redm[1]), fmaxf(redm[2], redm[3]));

    const float e0 = __expf(v.x - m), e1 = __expf(v.y - m);
    const float e2 = __expf(v.z - m), e3 = __expf(v.w - m);
    float s = e0 + e1 + e2 + e3;
#pragma unroll
    for (int o = 1; o < 64; o <<= 1) s += __shfl_xor(s, o);
    __shared__ float reds[4];
    if (lane == 0) reds[w] = s;
    __syncthreads();
    s = reds[0] + reds[1] + reds[2] + reds[3];
    const float inv = 1.0f / s;

    const uint64_t pk = (uint64_t)f2b(e0 * inv)
                      | ((uint64_t)f2b(e1 * inv) << 16)
                      | ((uint64_t)f2b(e2 * inv) << 32)
                      | ((uint64_t)f2b(e3 * inv) << 48);
    ((uint64_t*)(P + (row << 10)))[t] = pk;
}

// ---------------------------------------------------------------------------
// out[b][q][d] = P[b] . Vt[b]^T   (f32 out)
// ---------------------------------------------------------------------------
__global__ __launch_bounds__(512, 2)
void k_gemm_pv(const uint16_t* __restrict__ P, const uint16_t* __restrict__ Vt,
               float* __restrict__ out) {
    const int b = blockIdx.z;
    const int m0 = blockIdx.y * 256;
    const int n0 = blockIdx.x * 256;
    f32x4 acc[4][4][2] = {};
    gemm256_core(P + ((size_t)b << 20), Vt + ((size_t)b << 20), m0, n0, acc);

    float* Ob = out + ((size_t)b << 20);
    const int tid = threadIdx.x, lane = tid & 63, w = tid >> 6;
    const int wm = w >> 2, wn = w & 3, r16 = lane & 15, g = lane >> 4;
#pragma unroll
    for (int q = 0; q < 4; ++q)
#pragma unroll
        for (int fi = 0; fi < 4; ++fi)
#pragma unroll
            for (int fj = 0; fj < 2; ++fj) {
                const int col = n0 + ep_col(q, wn, r16, fj);
#pragma unroll
                for (int r = 0; r < 4; ++r) {
                    const int row = m0 + ep_row(q, wm, g, fi, r);
                    Ob[(size_t)row * 1024 + col] = acc[q][fi][fj][r];
                }
            }
}

// ---------------------------------------------------------------------------
extern "C" void kernel_launch(void* const* d_in, const int* in_sizes, int n_in,
                              void* d_out, int out_size, void* d_ws, size_t ws_size,
                              hipStream_t stream) {
    const float* x    = (const float*)d_in[0];   // [32][1024][1024]
    const float* W    = (const float*)d_in[1];   // [1024][3072]
    const float* bias = (const float*)d_in[2];   // [3072]
    float* out = (float*)d_out;

    char* ws = (char*)d_ws;
    const size_t MB = 1ull << 20;
    uint16_t* Wt = (uint16_t*)(ws);               //   6 MB: [3072][1024] bf16
    uint16_t* xb = (uint16_t*)(ws + 6   * MB);    //  64 MB: [32768][1024] bf16
    uint16_t* Qo = (uint16_t*)(ws + 70  * MB);    //  64 MB
    uint16_t* Ko = (uint16_t*)(ws + 134 * MB);    //  64 MB
    uint16_t* Vt = (uint16_t*)(ws + 198 * MB);    //  64 MB: [b][d][s]
    float*    S  = (float*)   (ws + 262 * MB);    // 128 MB: [b][q][k] f32
    uint16_t* P  = (uint16_t*)(ws + 390 * MB);    //  64 MB
    // total 454 MB of ws

    k_wt    <<<dim3(N3 / 32, KDIM / 32), dim3(32, 8), 0, stream>>>(W, Wt);
    k_convx <<<8192, 256, 0, stream>>>(x, xb);
    k_gemm_qkv<<<QKV_NWG, 512, 0, stream>>>(xb, Wt, bias, Qo, Ko, Vt);
    k_gemm_s  <<<dim3(SEQ / 256, SEQ / 256, BATCH), 512, 0, stream>>>(Qo, Ko, S);
    k_softmax <<<MTOT, 256, 0, stream>>>(S, P);
    k_gemm_pv <<<dim3(DIM / 256, SEQ / 256, BATCH), 512, 0, stream>>>(P, Vt, out);
}